// Round 10
// baseline (971.979 us; speedup 1.0000x reference)
//
#include <hip/hip_runtime.h>
#include <hip/hip_cooperative_groups.h>

namespace cg = cooperative_groups;

// ---------------------------------------------------------------------------
// GNNPerAgentModel — round 10: cooperative mega-kernel, LDS shrunk to 32 KB
// (2 blocks/CU under the 64 KB occupancy pool -> 512-block coop grid legal),
// plus an error-checked fallback to the round-8 multi-kernel path so a
// rejected cooperative launch can never produce a wrong answer.
// ---------------------------------------------------------------------------

typedef __attribute__((ext_vector_type(8))) short bf16x8;
typedef __attribute__((ext_vector_type(4))) float f32x4;

union U4 { uint4 v; unsigned int u[4]; bf16x8 h; };

__device__ __forceinline__ unsigned short f2bf(float x) {
    unsigned int u = __float_as_uint(x);
    return (unsigned short)((u + 0x7FFFu + ((u >> 16) & 1u)) >> 16);
}
__device__ __forceinline__ unsigned int pack2(float lo, float hi) {
    return (unsigned int)f2bf(lo) | ((unsigned int)f2bf(hi) << 16);
}
__device__ __forceinline__ bf16x8 loadA(const unsigned int* W, int k8, int M, int oc) {
    U4 r; r.v = *(const uint4*)(W + (((size_t)k8 * M + oc) << 2));
    return r.h;
}
__device__ __forceinline__ bf16x8 loadB4(const unsigned int* base, size_t idx) {
    U4 r; r.v = *(const uint4*)(base + (idx << 2));
    return r.h;
}
#define MFMA(a, b, c) __builtin_amdgcn_mfma_f32_16x16x32_bf16((a), (b), (c), 0, 0, 0)

__device__ __forceinline__ int xcd_swz(int L, int nwg) {
    int q = nwg >> 3, r = nwg & 7;
    int x = L & 7, i = L >> 3;
    return (x < r ? x * (q + 1) : r * (q + 1) + (x - r) * q) + i;
}
// k-panel store (variable BC for fallback kernels)
__device__ __forceinline__ void storeKb(unsigned int* out, size_t row, size_t BC,
                                        size_t bcol, int lg, unsigned int u0, unsigned int u1) {
    uint2 v; v.x = u0; v.y = u1;
    *(uint2*)(out + ((row * BC + bcol) << 2) + ((lg & 1) << 1)) = v;
}
// BC=512 fixed (coop kernel)
__device__ __forceinline__ void storeK(unsigned int* out, size_t row, size_t bcol,
                                       int lg, unsigned int u0, unsigned int u1) {
    storeKb(out, row, 512, bcol, lg, u0, u1);
}

// ===========================================================================
// Cooperative mega-kernel (BC = 512, smem = 32 KB exactly)
// ===========================================================================
__global__ __launch_bounds__(256, 2) void mega(
    const float* __restrict__ cam, const float* __restrict__ pos,
    const float* __restrict__ tpos, const int* __restrict__ aidx,
    const float* __restrict__ W1, const float* __restrict__ b1,
    const float* __restrict__ W2, const float* __restrict__ b2,
    const float* __restrict__ W3, const float* __restrict__ b3,
    const float* __restrict__ Wp, const float* __restrict__ bp,
    const float* __restrict__ Wid, const float* __restrict__ bidw,
    const float* __restrict__ Wg, const float* __restrict__ asrc,
    const float* __restrict__ adst, const float* __restrict__ Wh1,
    const float* __restrict__ bh1, const float* __restrict__ Wh2,
    const float* __restrict__ bh2, float* __restrict__ out,
    unsigned int* __restrict__ ws32)
{
    cg::grid_group grid = cg::this_grid();
    __shared__ __align__(16) float smem[8192];    // 32,768 B

    unsigned int* RA   = ws32;
    unsigned int* RB   = ws32 + 7225344u;
    unsigned int* RC   = ws32 + 19685376u;
    float*        RD   = (float*)(ws32 + 23879680u);
    unsigned int* W1t  = ws32 + 25976832u;
    unsigned int* W2t  = ws32 + 25980928u;
    unsigned int* W3t  = ws32 + 25997312u;
    unsigned int* Wpt  = ws32 + 26015744u;
    unsigned int* Wgt  = ws32 + 28112896u;
    unsigned int* Wh1t = ws32 + 28145664u;
    unsigned int* cf16 = ws32 + 28186624u;
    float*        hNb  = (float*)(ws32 + 28252160u);
    unsigned int* af16 = ws32 + 28383232u;

    const int tid = threadIdx.x;
    const int blk = blockIdx.x;
    const int nblk = gridDim.x;
    const int sblk = xcd_swz(blk, nblk);
    const int wv = tid >> 6, l = tid & 63, lg = l >> 4, lc = l & 15;

    // ---------------- P0a: weight prepack (grid-stride) ----------------
    for (int i = blk * 256 + tid; i < 2209792; i += nblk * 256) {
        if (i < 4096) {
            int j2 = i & 3, oc = (i >> 2) & 31, k8 = i >> 7;
            int kh = k8 >> 2, kwp = k8 & 3;
            float w[2];
            #pragma unroll
            for (int e = 0; e < 2; e++) {
                int jj = 2 * j2 + e;
                int kwlo = jj >> 2, c = jj & 3;
                w[e] = (c == 3) ? 0.f
                     : W1[((oc * 3 + c) * 8 + kh) * 8 + 2 * kwp + kwlo];
            }
            W1t[i] = pack2(w[0], w[1]);
        } else if (i < 20480) {
            int j = i - 4096;
            int j2 = j & 3, oc = (j >> 2) & 63, k8 = j >> 8;
            int tap = k8 >> 2, ic = (k8 & 3) * 8 + 2 * j2;
            int kh = tap >> 2, kw = tap & 3;
            float a = W2[((oc * 32 + ic) * 4 + kh) * 4 + kw];
            float b = W2[((oc * 32 + ic + 1) * 4 + kh) * 4 + kw];
            W2t[j] = pack2(a, b);
        } else if (i < 38912) {
            int j = i - 20480;
            int j2 = j & 3, oc = (j >> 2) & 63, k8 = j >> 8;
            int tap = k8 >> 3, ic = (k8 & 7) * 8 + 2 * j2;
            int kh = tap / 3, kw = tap % 3;
            float a = W3[((oc * 64 + ic) * 3 + kh) * 3 + kw];
            float b = W3[((oc * 64 + ic + 1) * 3 + kh) * 3 + kw];
            W3t[j] = pack2(a, b);
        } else if (i < 2136064) {
            int j = i - 38912;
            int j2 = j & 3, n = (j >> 2) & 255, k8 = j >> 10;
            int s3 = k8 >> 3, oc = (k8 & 7) * 8 + 2 * j2;
            float a = Wp[(size_t)(oc * 256 + s3) * 256 + n];
            float b = Wp[(size_t)((oc + 1) * 256 + s3) * 256 + n];
            Wpt[j] = pack2(a, b);
        } else if (i < 2168832) {
            int j = i - 2136064;
            int j2 = j & 3, m = (j >> 2) & 255, k8 = j >> 10;
            int k = k8 * 8 + 2 * j2;
            Wgt[j] = pack2(Wg[k * 256 + m], Wg[(k + 1) * 256 + m]);
        } else {
            int j = i - 2168832;
            int j2 = j & 3, m = (j >> 2) & 255, k8 = j >> 10;
            int k = k8 * 8 + 2 * j2;
            Wh1t[j] = pack2(Wh1[k * 256 + m], Wh1[(k + 1) * 256 + m]);
        }
    }
    // ---------------- P0b: cam transpose (16-batch tiles) ----------------
    {
        float (*lds)[253] = (float(*)[253])smem;      // 16 x 253 = 16,192 B
        for (int u = sblk; u < 2688; u += nblk) {     // 84 yy x 32 groups
            int yy = u % 84;
            int bb = (u / 84) * 16;
            __syncthreads();
            for (int f = tid; f < 4032; f += 256) {
                int b = f / 252, p = f - b * 252;
                lds[b][p] = cam[(size_t)(bb + b) * 21168 + yy * 252 + p];
            }
            __syncthreads();
            for (int g = tid; g < 672; g += 256) {
                int b = g & 15, xp = g >> 4;
                const float* lp = &lds[b][6 * xp];
                uint4 u4;
                u4.x = pack2(lp[0], lp[1]);
                u4.y = pack2(lp[2], 0.f);
                u4.z = pack2(lp[3], lp[4]);
                u4.w = pack2(lp[5], 0.f);
                *(uint4*)(RA + (((size_t)(yy * 42 + xp) * 512 + bb + b) << 2)) = u4;
            }
        }
    }
    __threadfence(); grid.sync();

    // ---------------- P1: conv1_pair (1560 units) ----------------
    for (int u = sblk; u < 1560; u += nblk) {
        int s = u % 780, bq = u / 780;
        int ohp = s / 39, ow = s - ohp * 39;
        int oh0 = 2 * ohp;
        const bool has2 = (oh0 + 1) < 39;
        size_t base = (size_t)bq * 256 + wv * 64 + lc;
        f32x4 acc0[2][4] = {}, acc1[2][4] = {};
        bf16x8 Ar0[2], Ar1[2];
        #pragma unroll
        for (int tt = 0; tt < 10; tt++) {
            const int par = tt & 1;
            bf16x8 B[4];
            if (tt < 8 || has2) {
                size_t row = (size_t)((2 * oh0 + tt) * 42 + ow + lg);
                #pragma unroll
                for (int g = 0; g < 4; g++)
                    B[g] = loadB4(RA, row * 512 + base + g * 16);
            }
            if (tt >= 2 && has2) {
                #pragma unroll
                for (int g = 0; g < 4; g++) {
                    acc1[0][g] = MFMA(Ar0[par], B[g], acc1[0][g]);
                    acc1[1][g] = MFMA(Ar1[par], B[g], acc1[1][g]);
                }
            }
            if (tt < 8) {
                bf16x8 An0 = loadA(W1t, tt * 4 + lg, 32, lc);
                bf16x8 An1 = loadA(W1t, tt * 4 + lg, 32, 16 + lc);
                #pragma unroll
                for (int g = 0; g < 4; g++) {
                    acc0[0][g] = MFMA(An0, B[g], acc0[0][g]);
                    acc0[1][g] = MFMA(An1, B[g], acc0[1][g]);
                }
                Ar0[par] = An0; Ar1[par] = An1;
            }
        }
        int s0 = oh0 * 39 + ow;
        #pragma unroll
        for (int m = 0; m < 2; m++) {
            float4 bv = *(const float4*)(b1 + m * 16 + lg * 4);
            size_t row = (size_t)s0 * 4 + 2 * m + (lg >> 1);
            #pragma unroll
            for (int g = 0; g < 4; g++) {
                f32x4 a = acc0[m][g];
                unsigned int u0 = pack2(fmaxf(a.x + bv.x, 0.f), fmaxf(a.y + bv.y, 0.f));
                unsigned int u1 = pack2(fmaxf(a.z + bv.z, 0.f), fmaxf(a.w + bv.w, 0.f));
                storeK(RB, row, base + g * 16, lg, u0, u1);
            }
            if (has2) {
                size_t row1 = row + 4 * 39;
                #pragma unroll
                for (int g = 0; g < 4; g++) {
                    f32x4 a = acc1[m][g];
                    unsigned int u0 = pack2(fmaxf(a.x + bv.x, 0.f), fmaxf(a.y + bv.y, 0.f));
                    unsigned int u1 = pack2(fmaxf(a.z + bv.z, 0.f), fmaxf(a.w + bv.w, 0.f));
                    storeK(RB, row1, base + g * 16, lg, u0, u1);
                }
            }
        }
    }
    __threadfence(); grid.sync();

    // ---------------- P2: conv2 (648 units) ----------------
    for (int u = sblk; u < 648; u += nblk) {
        int s = u % 324, bq = u / 324;
        int oh = s / 18, ow = s - oh * 18;
        size_t base = (size_t)bq * 256 + wv * 64 + lc;
        f32x4 acc[4][4] = {};
        int ybase = 2 * oh, xbase = 2 * ow;
        #pragma unroll 1
        for (int sp = 0; sp < 8; sp++) {
            const int s0 = 2 * sp, s1 = s0 + 1;
            bf16x8 A0[4], A1[4], B0[4], B1[4];
            #pragma unroll
            for (int m = 0; m < 4; m++) {
                A0[m] = loadA(W2t, s0 * 4 + lg, 64, m * 16 + lc);
                A1[m] = loadA(W2t, s1 * 4 + lg, 64, m * 16 + lc);
            }
            {
                const int kh = s0 >> 2, kw = s0 & 3;
                size_t row = (size_t)(((ybase + kh) * 39 + xbase + kw) * 4 + lg);
                #pragma unroll
                for (int g = 0; g < 4; g++)
                    B0[g] = loadB4(RB, row * 512 + base + g * 16);
            }
            {
                const int kh = s1 >> 2, kw = s1 & 3;
                size_t row = (size_t)(((ybase + kh) * 39 + xbase + kw) * 4 + lg);
                #pragma unroll
                for (int g = 0; g < 4; g++)
                    B1[g] = loadB4(RB, row * 512 + base + g * 16);
            }
            #pragma unroll
            for (int m = 0; m < 4; m++)
                #pragma unroll
                for (int g = 0; g < 4; g++)
                    acc[m][g] = MFMA(A0[m], B0[g], acc[m][g]);
            #pragma unroll
            for (int m = 0; m < 4; m++)
                #pragma unroll
                for (int g = 0; g < 4; g++)
                    acc[m][g] = MFMA(A1[m], B1[g], acc[m][g]);
        }
        #pragma unroll
        for (int m = 0; m < 4; m++) {
            float4 bv = *(const float4*)(b2 + m * 16 + lg * 4);
            size_t row = (size_t)s * 8 + 2 * m + (lg >> 1);
            #pragma unroll
            for (int g = 0; g < 4; g++) {
                f32x4 a = acc[m][g];
                unsigned int u0 = pack2(fmaxf(a.x + bv.x, 0.f), fmaxf(a.y + bv.y, 0.f));
                unsigned int u1 = pack2(fmaxf(a.z + bv.z, 0.f), fmaxf(a.w + bv.w, 0.f));
                storeK(RA, row, base + g * 16, lg, u0, u1);
            }
        }
    }
    __threadfence(); grid.sync();

    // ---------------- P3: conv3 (512 units) ----------------
    for (int u = sblk; u < 512; u += nblk) {
        int s = u % 256, bq = u / 256;
        int oh = s >> 4, ow = s & 15;
        size_t base = (size_t)bq * 256 + wv * 64 + lc;
        f32x4 acc[4][4] = {};
        #pragma unroll 1
        for (int sp = 0; sp < 9; sp++) {
            const int s0 = 2 * sp, s1 = s0 + 1;
            const int kh = sp / 3, kw = sp - kh * 3;
            bf16x8 A0[4], A1[4], B0[4], B1[4];
            #pragma unroll
            for (int m = 0; m < 4; m++) {
                A0[m] = loadA(W3t, s0 * 4 + lg, 64, m * 16 + lc);
                A1[m] = loadA(W3t, s1 * 4 + lg, 64, m * 16 + lc);
            }
            size_t row0 = (size_t)(((oh + kh) * 18 + ow + kw) * 8 + lg);
            #pragma unroll
            for (int g = 0; g < 4; g++) {
                B0[g] = loadB4(RA, row0 * 512 + base + g * 16);
                B1[g] = loadB4(RA, (row0 + 4) * 512 + base + g * 16);
            }
            #pragma unroll
            for (int m = 0; m < 4; m++)
                #pragma unroll
                for (int g = 0; g < 4; g++)
                    acc[m][g] = MFMA(A0[m], B0[g], acc[m][g]);
            #pragma unroll
            for (int m = 0; m < 4; m++)
                #pragma unroll
                for (int g = 0; g < 4; g++)
                    acc[m][g] = MFMA(A1[m], B1[g], acc[m][g]);
        }
        #pragma unroll
        for (int m = 0; m < 4; m++) {
            float4 bv = *(const float4*)(b3 + m * 16 + lg * 4);
            size_t row = (size_t)s * 8 + 2 * m + (lg >> 1);
            #pragma unroll
            for (int g = 0; g < 4; g++) {
                f32x4 a = acc[m][g];
                unsigned int u0 = pack2(fmaxf(a.x + bv.x, 0.f), fmaxf(a.y + bv.y, 0.f));
                unsigned int u1 = pack2(fmaxf(a.z + bv.z, 0.f), fmaxf(a.w + bv.w, 0.f));
                storeK(RC, row, base + g * 16, lg, u0, u1);
            }
        }
    }
    __threadfence(); grid.sync();

    // ---------------- P4: proj K-split 16 (256 units) ----------------
    for (int u = sblk; u < 256; u += nblk) {
        int rem = u & 63, b128 = u >> 6;
        int mq = rem & 3, kseg = rem >> 2;
        size_t base = (size_t)b128 * 128 + wv * 32 + lc;
        f32x4 acc[4][2] = {};
        #pragma unroll 1
        for (int sp = 0; sp < 16; sp++) {
            const int k8b = kseg * 128 + sp * 8;
            bf16x8 A0[4], A1[4], B0[2], B1[2];
            #pragma unroll
            for (int m = 0; m < 4; m++) {
                A0[m] = loadA(Wpt, k8b + lg, 256, mq * 64 + m * 16 + lc);
                A1[m] = loadA(Wpt, k8b + 4 + lg, 256, mq * 64 + m * 16 + lc);
            }
            #pragma unroll
            for (int g = 0; g < 2; g++) {
                B0[g] = loadB4(RC, (size_t)(k8b + lg) * 512 + base + g * 16);
                B1[g] = loadB4(RC, (size_t)(k8b + 4 + lg) * 512 + base + g * 16);
            }
            #pragma unroll
            for (int m = 0; m < 4; m++)
                #pragma unroll
                for (int g = 0; g < 2; g++)
                    acc[m][g] = MFMA(A0[m], B0[g], acc[m][g]);
            #pragma unroll
            for (int m = 0; m < 4; m++)
                #pragma unroll
                for (int g = 0; g < 2; g++)
                    acc[m][g] = MFMA(A1[m], B1[g], acc[m][g]);
        }
        #pragma unroll
        for (int m = 0; m < 4; m++) {
            size_t row4 = (size_t)kseg * 64 + mq * 16 + m * 4 + lg;
            #pragma unroll
            for (int g = 0; g < 2; g++)
                *(f32x4*)(RD + ((row4 * 512 + base + g * 16) << 2)) = acc[m][g];
        }
    }
    __threadfence(); grid.sync();

    // ---------------- P5: reduce ----------------
    for (int i = blk * 256 + tid; i < 16384; i += nblk * 256) {
        int bl = i & 511;
        int k8 = i >> 9;
        f32x4 S0 = {}, S1 = {};
        for (int seg = 0; seg < 16; seg++) {
            const float* p = RD + (((size_t)(seg * 64 + k8 * 2) * 512 + bl) << 2);
            S0 += *(const f32x4*)p;
            S1 += *(const f32x4*)(p + (512 << 2));
        }
        int n = k8 * 8;
        uint4 u;
        u.x = pack2(fmaxf(S0.x + bp[n + 0], 0.f), fmaxf(S0.y + bp[n + 1], 0.f));
        u.y = pack2(fmaxf(S0.z + bp[n + 2], 0.f), fmaxf(S0.w + bp[n + 3], 0.f));
        u.z = pack2(fmaxf(S1.x + bp[n + 4], 0.f), fmaxf(S1.y + bp[n + 5], 0.f));
        u.w = pack2(fmaxf(S1.z + bp[n + 6], 0.f), fmaxf(S1.w + bp[n + 7], 0.f));
        *(uint4*)(cf16 + (((size_t)k8 * 512 + bl) << 2)) = u;
    }
    __threadfence(); grid.sync();

    // ---------------- P6: gat_prep (64 wave units) ----------------
    for (int u = blk * 4 + wv; u < 64; u += nblk * 4) {
        int mq = u >> 4, bq = u & 15;
        size_t bcol = (size_t)bq * 32 + lc;
        f32x4 acc[4][2] = {};
        #pragma unroll
        for (int sp = 0; sp < 4; sp++) {
            const int s0 = 2 * sp, s1 = s0 + 1;
            bf16x8 A0[4], A1[4], B0[2], B1[2];
            #pragma unroll
            for (int m = 0; m < 4; m++) {
                A0[m] = loadA(Wgt, s0 * 4 + lg, 256, mq * 64 + m * 16 + lc);
                A1[m] = loadA(Wgt, s1 * 4 + lg, 256, mq * 64 + m * 16 + lc);
            }
            #pragma unroll
            for (int g = 0; g < 2; g++) {
                B0[g] = loadB4(cf16, (size_t)(s0 * 4 + lg) * 512 + bcol + g * 16);
                B1[g] = loadB4(cf16, (size_t)(s1 * 4 + lg) * 512 + bcol + g * 16);
            }
            #pragma unroll
            for (int m = 0; m < 4; m++) {
                acc[m][0] = MFMA(A0[m], B0[0], acc[m][0]);
                acc[m][1] = MFMA(A0[m], B0[1], acc[m][1]);
                acc[m][0] = MFMA(A1[m], B1[0], acc[m][0]);
                acc[m][1] = MFMA(A1[m], B1[1], acc[m][1]);
            }
        }
        #pragma unroll
        for (int m = 0; m < 4; m++) {
            #pragma unroll
            for (int g = 0; g < 2; g++) {
                size_t b = (size_t)bq * 32 + g * 16 + lc;
                int row0 = mq * 64 + m * 16 + lg * 4;
                *(f32x4*)(hNb + b * 256 + row0) = acc[m][g];
            }
        }
    }
    __threadfence(); grid.sync();

    // ---------------- P7: gat_mid (512 units) ----------------
    {
        float (*hN)[256] = (float(*)[256])smem;
        float* srcv  = smem + 4096;
        float* dstv  = smem + 4128;
        float* alpha = smem + 4160;
        float* af    = smem + 4192;
        unsigned int* adjm_s = (unsigned int*)(smem + 4512);
        for (int u = blk; u < 512; u += nblk) {
            int b = u;
            __syncthreads();
            int ai = aidx[b];
            float basev = hNb[(size_t)b * 256 + tid];
            float rw0 = Wg[65536 + tid], rw1 = Wg[65792 + tid], rw2 = Wg[66048 + tid];
            float px = pos[b * 3 + 0], py = pos[b * 3 + 1], pz = pos[b * 3 + 2];
            for (int n = 0; n < 16; n++) {
                float r0 = tpos[(b * 16 + n) * 3 + 0] - px;
                float r1 = tpos[(b * 16 + n) * 3 + 1] - py;
                float r2 = tpos[(b * 16 + n) * 3 + 2] - pz;
                hN[n][tid] = basev + r0 * rw0 + r1 * rw1 + r2 * rw2;
            }
            if (tid < 64) {
                bool on = false;
                if (tid < 16 && tid != ai) {
                    float dx = tpos[(b * 16 + ai) * 3 + 0] - tpos[(b * 16 + tid) * 3 + 0];
                    float dy = tpos[(b * 16 + ai) * 3 + 1] - tpos[(b * 16 + tid) * 3 + 1];
                    float dz = tpos[(b * 16 + ai) * 3 + 2] - tpos[(b * 16 + tid) * 3 + 2];
                    on = (dx * dx + dy * dy + dz * dz) < 10000.0f;
                }
                unsigned long long m = __ballot(on);
                if (tid == 0) *adjm_s = (m == 0ull) ? (1u << ai) : (unsigned int)m;
            }
            __syncthreads();
            {
                int p = tid >> 3, sub = tid & 7;
                int j = p >> 1, h = p & 1;
                float s1 = 0.f, s2 = 0.f;
                #pragma unroll
                for (int dd = 0; dd < 16; dd++) {
                    int d = h * 128 + sub * 16 + dd;
                    float v = hN[j][d];
                    s1 += v * asrc[d];
                    s2 += v * adst[d];
                }
                s1 += __shfl_xor(s1, 1); s1 += __shfl_xor(s1, 2); s1 += __shfl_xor(s1, 4);
                s2 += __shfl_xor(s2, 1); s2 += __shfl_xor(s2, 2); s2 += __shfl_xor(s2, 4);
                if (sub == 0) { srcv[j * 2 + h] = s1; dstv[j * 2 + h] = s2; }
            }
            __syncthreads();
            if (tid < 32) {
                int j = tid & 15, h = tid >> 4;
                unsigned int am = *adjm_s;
                float e = srcv[ai * 2 + h] + dstv[j * 2 + h];
                e = (e > 0.f) ? e : 0.2f * e;
                e = ((am >> j) & 1u) ? e : -1e9f;
                float mx = e;
                mx = fmaxf(mx, __shfl_xor(mx, 1));
                mx = fmaxf(mx, __shfl_xor(mx, 2));
                mx = fmaxf(mx, __shfl_xor(mx, 4));
                mx = fmaxf(mx, __shfl_xor(mx, 8));
                float ex = __expf(e - mx);
                float sm = ex;
                sm += __shfl_xor(sm, 1); sm += __shfl_xor(sm, 2);
                sm += __shfl_xor(sm, 4); sm += __shfl_xor(sm, 8);
                alpha[j * 2 + h] = ex / sm;
            }
            __syncthreads();
            {
                int h = tid >> 7;
                float o = 0.f;
                #pragma unroll
                for (int j = 0; j < 16; j++) o += alpha[j * 2 + h] * hN[j][tid];
                o = (o > 0.f) ? o : (__expf(o) - 1.f);
                af[tid] = o;
            }
            if (tid < 64) {
                float v = (float)aidx[b] * Wid[tid] + bidw[tid];
                af[256 + tid] = fmaxf(v, 0.f);
            }
            __syncthreads();
            if (tid < 40) {
                uint4 u4;
                u4.x = pack2(af[tid * 8 + 0], af[tid * 8 + 1]);
                u4.y = pack2(af[tid * 8 + 2], af[tid * 8 + 3]);
                u4.z = pack2(af[tid * 8 + 4], af[tid * 8 + 5]);
                u4.w = pack2(af[tid * 8 + 6], af[tid * 8 + 7]);
                *(uint4*)(af16 + (((size_t)tid * 512 + b) << 2)) = u4;
            }
        }
    }
    __threadfence(); grid.sync();

    // ---------------- P8: head + logits (16 units) ----------------
    {
        float (*zfs)[32] = (float(*)[32])smem;        // 8192 floats = 32 KB
        for (int u = blk; u < 16; u += nblk) {
            int bq = u;
            __syncthreads();
            size_t bcol = (size_t)bq * 32 + lc;
            int mq = wv;
            f32x4 acc[4][2] = {};
            #pragma unroll
            for (int sp = 0; sp < 5; sp++) {
                const int s0 = 2 * sp, s1 = s0 + 1;
                bf16x8 A0[4], A1[4], B0[2], B1[2];
                #pragma unroll
                for (int m = 0; m < 4; m++) {
                    A0[m] = loadA(Wh1t, s0 * 4 + lg, 256, mq * 64 + m * 16 + lc);
                    A1[m] = loadA(Wh1t, s1 * 4 + lg, 256, mq * 64 + m * 16 + lc);
                }
                #pragma unroll
                for (int g = 0; g < 2; g++) {
                    B0[g] = loadB4(af16, (size_t)(s0 * 4 + lg) * 512 + bcol + g * 16);
                    B1[g] = loadB4(af16, (size_t)(s1 * 4 + lg) * 512 + bcol + g * 16);
                }
                #pragma unroll
                for (int m = 0; m < 4; m++) {
                    acc[m][0] = MFMA(A0[m], B0[0], acc[m][0]);
                    acc[m][1] = MFMA(A0[m], B0[1], acc[m][1]);
                    acc[m][0] = MFMA(A1[m], B1[0], acc[m][0]);
                    acc[m][1] = MFMA(A1[m], B1[1], acc[m][1]);
                }
            }
            #pragma unroll
            for (int m = 0; m < 4; m++) {
                int row0 = mq * 64 + m * 16 + lg * 4;
                float4 bv = *(const float4*)(bh1 + row0);
                #pragma unroll
                for (int g = 0; g < 2; g++) {
                    f32x4 a = acc[m][g];
                    int bl = g * 16 + lc;
                    zfs[row0 + 0][bl] = fmaxf(a.x + bv.x, 0.f);
                    zfs[row0 + 1][bl] = fmaxf(a.y + bv.y, 0.f);
                    zfs[row0 + 2][bl] = fmaxf(a.z + bv.z, 0.f);
                    zfs[row0 + 3][bl] = fmaxf(a.w + bv.w, 0.f);
                }
            }
            __syncthreads();
            if (tid < 192) {
                int b = tid & 31, j = tid >> 5;
                float s = bh2[j];
                #pragma unroll 8
                for (int k = 0; k < 256; k++) s += zfs[k][b] * Wh2[k * 6 + j];
                out[(bq * 32 + b) * 6 + j] = s;
            }
        }
    }
}

// ===========================================================================
// Fallback: round-8 multi-kernel path (verbatim)
// ===========================================================================
__global__ __launch_bounds__(256) void prepack(
    const float* __restrict__ W1, const float* __restrict__ W2,
    const float* __restrict__ W3, const float* __restrict__ Wp,
    const float* __restrict__ Wg, const float* __restrict__ Wh1,
    unsigned int* __restrict__ W1t, unsigned int* __restrict__ W2t,
    unsigned int* __restrict__ W3t, unsigned int* __restrict__ Wpt,
    unsigned int* __restrict__ Wgt, unsigned int* __restrict__ Wh1t)
{
    int i = blockIdx.x * 256 + threadIdx.x;
    if (i < 4096) {
        int j2 = i & 3, oc = (i >> 2) & 31, k8 = i >> 7;
        int kh = k8 >> 2, kwp = k8 & 3;
        float w[2];
        #pragma unroll
        for (int e = 0; e < 2; e++) {
            int jj = 2 * j2 + e;
            int kwlo = jj >> 2, c = jj & 3;
            w[e] = (c == 3) ? 0.f
                 : W1[((oc * 3 + c) * 8 + kh) * 8 + 2 * kwp + kwlo];
        }
        W1t[i] = pack2(w[0], w[1]);
    } else if (i < 20480) {
        int j = i - 4096;
        int j2 = j & 3, oc = (j >> 2) & 63, k8 = j >> 8;
        int tap = k8 >> 2, ic = (k8 & 3) * 8 + 2 * j2;
        int kh = tap >> 2, kw = tap & 3;
        float a = W2[((oc * 32 + ic) * 4 + kh) * 4 + kw];
        float b = W2[((oc * 32 + ic + 1) * 4 + kh) * 4 + kw];
        W2t[j] = pack2(a, b);
    } else if (i < 38912) {
        int j = i - 20480;
        int j2 = j & 3, oc = (j >> 2) & 63, k8 = j >> 8;
        int tap = k8 >> 3, ic = (k8 & 7) * 8 + 2 * j2;
        int kh = tap / 3, kw = tap % 3;
        float a = W3[((oc * 64 + ic) * 3 + kh) * 3 + kw];
        float b = W3[((oc * 64 + ic + 1) * 3 + kh) * 3 + kw];
        W3t[j] = pack2(a, b);
    } else if (i < 2136064) {
        int j = i - 38912;
        int j2 = j & 3, n = (j >> 2) & 255, k8 = j >> 10;
        int s3 = k8 >> 3, oc = (k8 & 7) * 8 + 2 * j2;
        float a = Wp[(size_t)(oc * 256 + s3) * 256 + n];
        float b = Wp[(size_t)((oc + 1) * 256 + s3) * 256 + n];
        Wpt[j] = pack2(a, b);
    } else if (i < 2168832) {
        int j = i - 2136064;
        int j2 = j & 3, m = (j >> 2) & 255, k8 = j >> 10;
        int k = k8 * 8 + 2 * j2;
        Wgt[j] = pack2(Wg[k * 256 + m], Wg[(k + 1) * 256 + m]);
    } else if (i < 2209792) {
        int j = i - 2168832;
        int j2 = j & 3, m = (j >> 2) & 255, k8 = j >> 10;
        int k = k8 * 8 + 2 * j2;
        Wh1t[j] = pack2(Wh1[k * 256 + m], Wh1[(k + 1) * 256 + m]);
    }
}

__global__ __launch_bounds__(256) void transpose_cam(
    const float* __restrict__ cam, unsigned int* __restrict__ camq, int b0, int BC)
{
    __shared__ float lds[32][253];
    int yy = blockIdx.x;
    int bb = blockIdx.y * 32;
    int t = threadIdx.x;
    for (int f = t; f < 8064; f += 256) {
        int b = f / 252, p = f - b * 252;
        lds[b][p] = cam[(size_t)(b0 + bb + b) * 21168 + yy * 252 + p];
    }
    __syncthreads();
    for (int g = t; g < 1344; g += 256) {
        int b = g & 31, xp = g >> 5;
        const float* l = &lds[b][6 * xp];
        uint4 u;
        u.x = pack2(l[0], l[1]);
        u.y = pack2(l[2], 0.f);
        u.z = pack2(l[3], l[4]);
        u.w = pack2(l[5], 0.f);
        *(uint4*)(camq + (((size_t)(yy * 42 + xp) * BC + bb + b) << 2)) = u;
    }
}

__global__ __launch_bounds__(256, 3) void conv1_pair(
    const unsigned int* __restrict__ in32, const unsigned int* __restrict__ Wt,
    const float* __restrict__ bias, unsigned int* __restrict__ out32,
    int BC, int nspat)
{
    int wgid = xcd_swz(blockIdx.x, gridDim.x);
    int s = wgid % nspat;
    int bq = wgid / nspat;
    int ohp = s / 39, ow = s - ohp * 39;
    int oh0 = 2 * ohp;
    const bool has2 = (oh0 + 1) < 39;
    int wv = threadIdx.x >> 6, l = threadIdx.x & 63;
    int lg = l >> 4, lc = l & 15;
    const size_t sBC = (size_t)BC;
    size_t base = (size_t)bq * 256 + wv * 64 + lc;
    f32x4 acc0[2][4] = {}, acc1[2][4] = {};
    bf16x8 Ar0[2], Ar1[2];
    #pragma unroll
    for (int t = 0; t < 10; t++) {
        const int par = t & 1;
        bf16x8 B[4];
        if (t < 8 || has2) {
            size_t row = (size_t)((2 * oh0 + t) * 42 + ow + lg);
            #pragma unroll
            for (int g = 0; g < 4; g++)
                B[g] = loadB4(in32, row * sBC + base + g * 16);
        }
        if (t >= 2 && has2) {
            #pragma unroll
            for (int g = 0; g < 4; g++) {
                acc1[0][g] = MFMA(Ar0[par], B[g], acc1[0][g]);
                acc1[1][g] = MFMA(Ar1[par], B[g], acc1[1][g]);
            }
        }
        if (t < 8) {
            bf16x8 An0 = loadA(Wt, t * 4 + lg, 32, lc);
            bf16x8 An1 = loadA(Wt, t * 4 + lg, 32, 16 + lc);
            #pragma unroll
            for (int g = 0; g < 4; g++) {
                acc0[0][g] = MFMA(An0, B[g], acc0[0][g]);
                acc0[1][g] = MFMA(An1, B[g], acc0[1][g]);
            }
            Ar0[par] = An0; Ar1[par] = An1;
        }
    }
    int s0 = oh0 * 39 + ow;
    #pragma unroll
    for (int m = 0; m < 2; m++) {
        float4 bv = *(const float4*)(bias + m * 16 + lg * 4);
        size_t row = (size_t)s0 * 4 + 2 * m + (lg >> 1);
        #pragma unroll
        for (int g = 0; g < 4; g++) {
            f32x4 a = acc0[m][g];
            unsigned int u0 = pack2(fmaxf(a.x + bv.x, 0.f), fmaxf(a.y + bv.y, 0.f));
            unsigned int u1 = pack2(fmaxf(a.z + bv.z, 0.f), fmaxf(a.w + bv.w, 0.f));
            storeKb(out32, row, sBC, base + g * 16, lg, u0, u1);
        }
        if (has2) {
            size_t row1 = row + 4 * 39;
            #pragma unroll
            for (int g = 0; g < 4; g++) {
                f32x4 a = acc1[m][g];
                unsigned int u0 = pack2(fmaxf(a.x + bv.x, 0.f), fmaxf(a.y + bv.y, 0.f));
                unsigned int u1 = pack2(fmaxf(a.z + bv.z, 0.f), fmaxf(a.w + bv.w, 0.f));
                storeKb(out32, row1, sBC, base + g * 16, lg, u0, u1);
            }
        }
    }
}

__global__ __launch_bounds__(128, 3) void conv2_mfma(
    const unsigned int* __restrict__ in32, const unsigned int* __restrict__ Wt,
    const float* __restrict__ bias, unsigned int* __restrict__ out32,
    int BC, int nspat)
{
    int wgid = xcd_swz(blockIdx.x, gridDim.x);
    int s = wgid % nspat;
    int bq = wgid / nspat;
    int oh = s / 18, ow = s - oh * 18;
    int wv = threadIdx.x >> 6, l = threadIdx.x & 63;
    int lg = l >> 4, lc = l & 15;
    const size_t sBC = (size_t)BC;
    size_t base = (size_t)bq * 128 + wv * 64 + lc;
    f32x4 acc[4][4] = {};
    int ybase = 2 * oh, xbase = 2 * ow;
    #pragma unroll 1
    for (int sp = 0; sp < 8; sp++) {
        const int s0 = 2 * sp, s1 = s0 + 1;
        bf16x8 A0[4], A1[4], B0[4], B1[4];
        #pragma unroll
        for (int m = 0; m < 4; m++) {
            A0[m] = loadA(Wt, s0 * 4 + lg, 64, m * 16 + lc);
            A1[m] = loadA(Wt, s1 * 4 + lg, 64, m * 16 + lc);
        }
        {
            const int kh = s0 >> 2, kw = s0 & 3;
            size_t row = (size_t)(((ybase + kh) * 39 + xbase + kw) * 4 + lg);
            #pragma unroll
            for (int g = 0; g < 4; g++)
                B0[g] = loadB4(in32, row * sBC + base + g * 16);
        }
        {
            const int kh = s1 >> 2, kw = s1 & 3;
            size_t row = (size_t)(((ybase + kh) * 39 + xbase + kw) * 4 + lg);
            #pragma unroll
            for (int g = 0; g < 4; g++)
                B1[g] = loadB4(in32, row * sBC + base + g * 16);
        }
        #pragma unroll
        for (int m = 0; m < 4; m++)
            #pragma unroll
            for (int g = 0; g < 4; g++)
                acc[m][g] = MFMA(A0[m], B0[g], acc[m][g]);
        #pragma unroll
        for (int m = 0; m < 4; m++)
            #pragma unroll
            for (int g = 0; g < 4; g++)
                acc[m][g] = MFMA(A1[m], B1[g], acc[m][g]);
    }
    #pragma unroll
    for (int m = 0; m < 4; m++) {
        float4 bv = *(const float4*)(bias + m * 16 + lg * 4);
        size_t row = (size_t)s * 8 + 2 * m + (lg >> 1);
        #pragma unroll
        for (int g = 0; g < 4; g++) {
            f32x4 a = acc[m][g];
            unsigned int u0 = pack2(fmaxf(a.x + bv.x, 0.f), fmaxf(a.y + bv.y, 0.f));
            unsigned int u1 = pack2(fmaxf(a.z + bv.z, 0.f), fmaxf(a.w + bv.w, 0.f));
            storeKb(out32, row, sBC, base + g * 16, lg, u0, u1);
        }
    }
}

__global__ __launch_bounds__(128, 3) void conv3_mfma(
    const unsigned int* __restrict__ in32, const unsigned int* __restrict__ Wt,
    const float* __restrict__ bias, unsigned int* __restrict__ out32,
    int BC, int nspat)
{
    int wgid = xcd_swz(blockIdx.x, gridDim.x);
    int s = wgid % nspat;
    int bq = wgid / nspat;
    int oh = s >> 4, ow = s & 15;
    int wv = threadIdx.x >> 6, l = threadIdx.x & 63;
    int lg = l >> 4, lc = l & 15;
    const size_t sBC = (size_t)BC;
    size_t base = (size_t)bq * 128 + wv * 64 + lc;
    f32x4 acc[4][4] = {};
    #pragma unroll 1
    for (int sp = 0; sp < 9; sp++) {
        const int s0 = 2 * sp, s1 = s0 + 1;
        const int kh = sp / 3, kw = sp - kh * 3;
        bf16x8 A0[4], A1[4], B0[4], B1[4];
        #pragma unroll
        for (int m = 0; m < 4; m++) {
            A0[m] = loadA(Wt, s0 * 4 + lg, 64, m * 16 + lc);
            A1[m] = loadA(Wt, s1 * 4 + lg, 64, m * 16 + lc);
        }
        size_t row0 = (size_t)(((oh + kh) * 18 + ow + kw) * 8 + lg);
        #pragma unroll
        for (int g = 0; g < 4; g++) {
            B0[g] = loadB4(in32, row0 * sBC + base + g * 16);
            B1[g] = loadB4(in32, (row0 + 4) * sBC + base + g * 16);
        }
        #pragma unroll
        for (int m = 0; m < 4; m++)
            #pragma unroll
            for (int g = 0; g < 4; g++)
                acc[m][g] = MFMA(A0[m], B0[g], acc[m][g]);
        #pragma unroll
        for (int m = 0; m < 4; m++)
            #pragma unroll
            for (int g = 0; g < 4; g++)
                acc[m][g] = MFMA(A1[m], B1[g], acc[m][g]);
    }
    #pragma unroll
    for (int m = 0; m < 4; m++) {
        float4 bv = *(const float4*)(bias + m * 16 + lg * 4);
        size_t row = (size_t)s * 8 + 2 * m + (lg >> 1);
        #pragma unroll
        for (int g = 0; g < 4; g++) {
            f32x4 a = acc[m][g];
            unsigned int u0 = pack2(fmaxf(a.x + bv.x, 0.f), fmaxf(a.y + bv.y, 0.f));
            unsigned int u1 = pack2(fmaxf(a.z + bv.z, 0.f), fmaxf(a.w + bv.w, 0.f));
            storeKb(out32, row, sBC, base + g * 16, lg, u0, u1);
        }
    }
}

__global__ __launch_bounds__(128, 3) void proj_mfma(
    const unsigned int* __restrict__ x3, const unsigned int* __restrict__ Wpt,
    float* __restrict__ partial, int BC)
{
    int wgid = xcd_swz(blockIdx.x, gridDim.x);
    int rem = wgid & 63;
    int b64 = wgid >> 6;
    int mq = rem & 3;
    int kseg = rem >> 2;
    int wv = threadIdx.x >> 6, l = threadIdx.x & 63;
    int lg = l >> 4, lc = l & 15;
    const size_t sBC = (size_t)BC;
    size_t base = (size_t)b64 * 64 + wv * 32 + lc;
    f32x4 acc[4][2] = {};
    #pragma unroll 1
    for (int sp = 0; sp < 16; sp++) {
        const int k8b = kseg * 128 + sp * 8;
        bf16x8 A0[4], A1[4], B0[2], B1[2];
        #pragma unroll
        for (int m = 0; m < 4; m++) {
            A0[m] = loadA(Wpt, k8b + lg, 256, mq * 64 + m * 16 + lc);
            A1[m] = loadA(Wpt, k8b + 4 + lg, 256, mq * 64 + m * 16 + lc);
        }
        #pragma unroll
        for (int g = 0; g < 2; g++) {
            B0[g] = loadB4(x3, (size_t)(k8b + lg) * sBC + base + g * 16);
            B1[g] = loadB4(x3, (size_t)(k8b + 4 + lg) * sBC + base + g * 16);
        }
        #pragma unroll
        for (int m = 0; m < 4; m++)
            #pragma unroll
            for (int g = 0; g < 2; g++)
                acc[m][g] = MFMA(A0[m], B0[g], acc[m][g]);
        #pragma unroll
        for (int m = 0; m < 4; m++)
            #pragma unroll
            for (int g = 0; g < 2; g++)
                acc[m][g] = MFMA(A1[m], B1[g], acc[m][g]);
    }
    #pragma unroll
    for (int m = 0; m < 4; m++) {
        size_t row4 = (size_t)kseg * 64 + mq * 16 + m * 4 + lg;
        #pragma unroll
        for (int g = 0; g < 2; g++)
            *(f32x4*)(partial + ((row4 * sBC + base + g * 16) << 2)) = acc[m][g];
    }
}

__global__ __launch_bounds__(256) void reduce_k(
    const float* __restrict__ partial, const float* __restrict__ bp,
    unsigned int* __restrict__ cf16, int b0, int BC, int bcShift)
{
    int i = blockIdx.x * 256 + threadIdx.x;
    int bl = i & (BC - 1);
    int k8 = i >> bcShift;
    f32x4 S0 = {}, S1 = {};
    for (int seg = 0; seg < 16; seg++) {
        const float* p = partial + (((size_t)(seg * 64 + k8 * 2) * BC + bl) << 2);
        S0 += *(const f32x4*)p;
        S1 += *(const f32x4*)(p + (BC << 2));
    }
    int n = k8 * 8;
    uint4 u;
    u.x = pack2(fmaxf(S0.x + bp[n + 0], 0.f), fmaxf(S0.y + bp[n + 1], 0.f));
    u.y = pack2(fmaxf(S0.z + bp[n + 2], 0.f), fmaxf(S0.w + bp[n + 3], 0.f));
    u.z = pack2(fmaxf(S1.x + bp[n + 4], 0.f), fmaxf(S1.y + bp[n + 5], 0.f));
    u.w = pack2(fmaxf(S1.z + bp[n + 6], 0.f), fmaxf(S1.w + bp[n + 7], 0.f));
    *(uint4*)(cf16 + (((size_t)k8 * 512 + b0 + bl) << 2)) = u;
}

__global__ __launch_bounds__(64) void gat_prep(
    const unsigned int* __restrict__ cf16, const unsigned int* __restrict__ Wgt,
    float* __restrict__ hNb)
{
    int mq = blockIdx.x, bq = blockIdx.y;
    int l = threadIdx.x, lg = l >> 4, lc = l & 15;
    size_t bcol = (size_t)bq * 32 + lc;
    f32x4 acc[4][2] = {};
    #pragma unroll
    for (int sp = 0; sp < 4; sp++) {
        const int s0 = 2 * sp, s1 = s0 + 1;
        bf16x8 A0[4], A1[4], B0[2], B1[2];
        #pragma unroll
        for (int m = 0; m < 4; m++) {
            A0[m] = loadA(Wgt, s0 * 4 + lg, 256, mq * 64 + m * 16 + lc);
            A1[m] = loadA(Wgt, s1 * 4 + lg, 256, mq * 64 + m * 16 + lc);
        }
        #pragma unroll
        for (int g = 0; g < 2; g++) {
            B0[g] = loadB4(cf16, (size_t)(s0 * 4 + lg) * 512 + bcol + g * 16);
            B1[g] = loadB4(cf16, (size_t)(s1 * 4 + lg) * 512 + bcol + g * 16);
        }
        #pragma unroll
        for (int m = 0; m < 4; m++) {
            acc[m][0] = MFMA(A0[m], B0[0], acc[m][0]);
            acc[m][1] = MFMA(A0[m], B0[1], acc[m][1]);
            acc[m][0] = MFMA(A1[m], B1[0], acc[m][0]);
            acc[m][1] = MFMA(A1[m], B1[1], acc[m][1]);
        }
    }
    #pragma unroll
    for (int m = 0; m < 4; m++) {
        #pragma unroll
        for (int g = 0; g < 2; g++) {
            size_t b = (size_t)bq * 32 + g * 16 + lc;
            int row0 = mq * 64 + m * 16 + lg * 4;
            *(f32x4*)(hNb + b * 256 + row0) = acc[m][g];
        }
    }
}

__global__ __launch_bounds__(256) void gat_mid(
    const float* __restrict__ hNb, const float* __restrict__ pos,
    const float* __restrict__ tpos, const int* __restrict__ aidx,
    const float* __restrict__ Wg, const float* __restrict__ asrc, const float* __restrict__ adst,
    const float* __restrict__ Wid, const float* __restrict__ bid,
    unsigned int* __restrict__ af16)
{
    int b = blockIdx.x, t = threadIdx.x;
    __shared__ float hN[16][256];
    __shared__ float srcv[16][2], dstv[16][2];
    __shared__ float alpha[16][2];
    __shared__ float af[320];
    __shared__ unsigned int adjm_s;

    int ai = aidx[b];
    float basev = hNb[(size_t)b * 256 + t];
    float rw0 = Wg[65536 + t], rw1 = Wg[65792 + t], rw2 = Wg[66048 + t];
    float px = pos[b * 3 + 0], py = pos[b * 3 + 1], pz = pos[b * 3 + 2];
    for (int n = 0; n < 16; n++) {
        float r0 = tpos[(b * 16 + n) * 3 + 0] - px;
        float r1 = tpos[(b * 16 + n) * 3 + 1] - py;
        float r2 = tpos[(b * 16 + n) * 3 + 2] - pz;
        hN[n][t] = basev + r0 * rw0 + r1 * rw1 + r2 * rw2;
    }

    if (t < 64) {
        bool on = false;
        if (t < 16 && t != ai) {
            float dx = tpos[(b * 16 + ai) * 3 + 0] - tpos[(b * 16 + t) * 3 + 0];
            float dy = tpos[(b * 16 + ai) * 3 + 1] - tpos[(b * 16 + t) * 3 + 1];
            float dz = tpos[(b * 16 + ai) * 3 + 2] - tpos[(b * 16 + t) * 3 + 2];
            on = (dx * dx + dy * dy + dz * dz) < 10000.0f;
        }
        unsigned long long m = __ballot(on);
        if (t == 0) adjm_s = (m == 0ull) ? (1u << ai) : (unsigned int)m;
    }
    __syncthreads();

    {
        int p = t >> 3, sub = t & 7;
        int j = p >> 1, h = p & 1;
        float s1 = 0.f, s2 = 0.f;
        #pragma unroll
        for (int dd = 0; dd < 16; dd++) {
            int d = h * 128 + sub * 16 + dd;
            float v = hN[j][d];
            s1 += v * asrc[d];
            s2 += v * adst[d];
        }
        s1 += __shfl_xor(s1, 1); s1 += __shfl_xor(s1, 2); s1 += __shfl_xor(s1, 4);
        s2 += __shfl_xor(s2, 1); s2 += __shfl_xor(s2, 2); s2 += __shfl_xor(s2, 4);
        if (sub == 0) { srcv[j][h] = s1; dstv[j][h] = s2; }
    }
    __syncthreads();

    if (t < 32) {
        int j = t & 15, h = t >> 4;
        unsigned int am = adjm_s;
        float e = srcv[ai][h] + dstv[j][h];
        e = (e > 0.f) ? e : 0.2f * e;
        e = ((am >> j) & 1u) ? e : -1e9f;
        float mx = e;
        mx = fmaxf(mx, __shfl_xor(mx, 1));
        mx = fmaxf(mx, __shfl_xor(mx, 2));
        mx = fmaxf(mx, __shfl_xor(mx, 4));
        mx = fmaxf(mx, __shfl_xor(mx, 8));
        float ex = __expf(e - mx);
        float sm = ex;
        sm += __shfl_xor(sm, 1); sm += __shfl_xor(sm, 2);
        sm += __shfl_xor(sm, 4); sm += __shfl_xor(sm, 8);
        alpha[j][h] = ex / sm;
    }
    __syncthreads();

    {
        int h = t >> 7;
        float o = 0.f;
        #pragma unroll
        for (int j = 0; j < 16; j++) o += alpha[j][h] * hN[j][t];
        o = (o > 0.f) ? o : (__expf(o) - 1.f);
        af[t] = o;
    }
    if (t < 64) {
        float v = (float)ai * Wid[t] + bid[t];
        af[256 + t] = fmaxf(v, 0.f);
    }
    __syncthreads();

    if (t < 40) {
        uint4 u;
        u.x = pack2(af[t * 8 + 0], af[t * 8 + 1]);
        u.y = pack2(af[t * 8 + 2], af[t * 8 + 3]);
        u.z = pack2(af[t * 8 + 4], af[t * 8 + 5]);
        u.w = pack2(af[t * 8 + 6], af[t * 8 + 7]);
        *(uint4*)(af16 + (((size_t)t * 512 + b) << 2)) = u;
    }
}

__global__ __launch_bounds__(256) void head_logits(
    const unsigned int* __restrict__ af16, const unsigned int* __restrict__ Wh1t,
    const float* __restrict__ bh1, const float* __restrict__ Wh2,
    const float* __restrict__ bh2, float* __restrict__ out)
{
    __shared__ float zfs[256][32];
    __shared__ float Ws[1536];
    int bq = blockIdx.x;
    int t = threadIdx.x;
    int mq = t >> 6, l = t & 63, lg = l >> 4, lc = l & 15;
    for (int f = t; f < 1536; f += 256) Ws[f] = Wh2[f];

    size_t bcol = (size_t)bq * 32 + lc;
    f32x4 acc[4][2] = {};
    #pragma unroll
    for (int sp = 0; sp < 5; sp++) {
        const int s0 = 2 * sp, s1 = s0 + 1;
        bf16x8 A0[4], A1[4], B0[2], B1[2];
        #pragma unroll
        for (int m = 0; m < 4; m++) {
            A0[m] = loadA(Wh1t, s0 * 4 + lg, 256, mq * 64 + m * 16 + lc);
            A1[m] = loadA(Wh1t, s1 * 4 + lg, 256, mq * 64 + m * 16 + lc);
        }
        #pragma unroll
        for (int g = 0; g < 2; g++) {
            B0[g] = loadB4(af16, (size_t)(s0 * 4 + lg) * 512 + bcol + g * 16);
            B1[g] = loadB4(af16, (size_t)(s1 * 4 + lg) * 512 + bcol + g * 16);
        }
        #pragma unroll
        for (int m = 0; m < 4; m++) {
            acc[m][0] = MFMA(A0[m], B0[0], acc[m][0]);
            acc[m][1] = MFMA(A0[m], B0[1], acc[m][1]);
            acc[m][0] = MFMA(A1[m], B1[0], acc[m][0]);
            acc[m][1] = MFMA(A1[m], B1[1], acc[m][1]);
        }
    }
    #pragma unroll
    for (int m = 0; m < 4; m++) {
        int row0 = mq * 64 + m * 16 + lg * 4;
        float4 bv = *(const float4*)(bh1 + row0);
        #pragma unroll
        for (int g = 0; g < 2; g++) {
            f32x4 a = acc[m][g];
            int bl = g * 16 + lc;
            zfs[row0 + 0][bl] = fmaxf(a.x + bv.x, 0.f);
            zfs[row0 + 1][bl] = fmaxf(a.y + bv.y, 0.f);
            zfs[row0 + 2][bl] = fmaxf(a.z + bv.z, 0.f);
            zfs[row0 + 3][bl] = fmaxf(a.w + bv.w, 0.f);
        }
    }
    __syncthreads();

    if (t < 192) {
        int b = t & 31, j = t >> 5;
        float s = bh2[j];
        #pragma unroll 8
        for (int k = 0; k < 256; k++) s += zfs[k][b] * Ws[k * 6 + j];
        out[(bq * 32 + b) * 6 + j] = s;
    }
}

extern "C" void kernel_launch(void* const* d_in, const int* in_sizes, int n_in,
                              void* d_out, int out_size, void* d_ws, size_t ws_size,
                              hipStream_t stream)
{
    const float* cam  = (const float*)d_in[0];
    const float* pos  = (const float*)d_in[1];
    const float* tpos = (const float*)d_in[2];
    const int*   aidx = (const int*)d_in[3];
    const float* W1   = (const float*)d_in[4];
    const float* b1   = (const float*)d_in[5];
    const float* W2   = (const float*)d_in[6];
    const float* b2   = (const float*)d_in[7];
    const float* W3   = (const float*)d_in[8];
    const float* b3   = (const float*)d_in[9];
    const float* Wp   = (const float*)d_in[10];
    const float* bp   = (const float*)d_in[11];
    const float* Wid  = (const float*)d_in[12];
    const float* bidw = (const float*)d_in[13];
    const float* Wg   = (const float*)d_in[14];
    const float* asrc = (const float*)d_in[15];
    const float* adst = (const float*)d_in[16];
    const float* Wh1  = (const float*)d_in[17];
    const float* bh1  = (const float*)d_in[18];
    const float* Wh2  = (const float*)d_in[19];
    const float* bh2  = (const float*)d_in[20];
    float* out = (float*)d_out;
    unsigned int* ws32 = (unsigned int*)d_ws;

    bool coop_ok = false;
    // mega needs BC=512 layout: 28,465,152 u32 = ~114 MB
    if ((size_t)28465152 * 4 <= ws_size) {
        void* kargs[] = {
            (void*)&cam, (void*)&pos, (void*)&tpos, (void*)&aidx,
            (void*)&W1, (void*)&b1, (void*)&W2, (void*)&b2,
            (void*)&W3, (void*)&b3, (void*)&Wp, (void*)&bp,
            (void*)&Wid, (void*)&bidw, (void*)&Wg, (void*)&asrc,
            (void*)&adst, (void*)&Wh1, (void*)&bh1, (void*)&Wh2,
            (void*)&bh2, (void*)&out, (void*)&ws32
        };
        hipError_t err = hipLaunchCooperativeKernel(
            (const void*)mega, dim3(512), dim3(256), kargs, 0, stream);
        coop_ok = (err == hipSuccess);
    }

    if (!coop_ok) {
        // -------- round-8 fallback path --------
        int BC = 256;
        if (((size_t)50736 * 512 + 2488320) * 4 <= ws_size) BC = 512;
        int bcShift = (BC == 512) ? 9 : 8;
        int nbq2 = BC >> 8;
        int nbq7 = BC >> 7;
        int nbq6 = BC >> 6;

        unsigned int* RA  = ws32;
        unsigned int* RB  = RA + (size_t)14112 * BC;
        unsigned int* RC  = RB + (size_t)24336 * BC;
        float*        RD  = (float*)(RC + (size_t)8192 * BC);
        unsigned int* W1t = (unsigned int*)(RD + (size_t)4096 * BC);
        unsigned int* W2t  = W1t + 4096;
        unsigned int* W3t  = W2t + 16384;
        unsigned int* Wpt  = W3t + 18432;
        unsigned int* Wgt  = Wpt + 2097152;
        unsigned int* Wh1t = Wgt + 32768;
        unsigned int* cf16 = Wh1t + 40960;
        float*        hNb  = (float*)(cf16 + 65536);
        unsigned int* af16 = (unsigned int*)(hNb + 131072);

        prepack<<<8632, 256, 0, stream>>>(W1, W2, W3, Wp, Wg, Wh1,
                                          W1t, W2t, W3t, Wpt, Wgt, Wh1t);
        for (int b0 = 0; b0 < 512; b0 += BC) {
            transpose_cam<<<dim3(84, BC / 32), 256, 0, stream>>>(cam, RA, b0, BC);
            conv1_pair<<<780 * nbq2, 256, 0, stream>>>(RA, W1t, b1, RB, BC, 780);
            conv2_mfma<<<324 * nbq7, 128, 0, stream>>>(RB, W2t, b2, RA, BC, 324);
            conv3_mfma<<<256 * nbq7, 128, 0, stream>>>(RA, W3t, b3, RC, BC, 256);
            proj_mfma<<<64 * nbq6, 128, 0, stream>>>(RC, Wpt, RD, BC);
            reduce_k<<<(32 * BC) / 256, 256, 0, stream>>>(RD, bp, cf16, b0, BC, bcShift);
        }
        gat_prep<<<dim3(4, 16), 64, 0, stream>>>(cf16, Wgt, hNb);
        gat_mid<<<512, 256, 0, stream>>>(hNb, pos, tpos, aidx, Wg, asrc, adst,
                                         Wid, bidw, af16);
        head_logits<<<16, 256, 0, stream>>>(af16, Wh1t, bh1, Wh2, bh2, out);
    }
}

// Round 11
// 146.598 us; speedup vs baseline: 6.6302x; 6.6302x over previous
//
#include <hip/hip_runtime.h>

// ---------------------------------------------------------------------------
// GNNPerAgentModel — round 11: revert to the round-8 multi-kernel pipeline
// (best known: 146.8 us). Round 9/10 measured that cooperative grid.sync()
// costs ~100 us/barrier on MI355X (global atomic spin across 8 non-coherent
// L2s): 8 syncs = +825 us, decisively worse than ~2-4 us dispatch boundaries.
// Conv chain = bf16 MFMA implicit-GEMM, k-panel activations (uint4 = 8 bf16 k).
// ---------------------------------------------------------------------------

typedef __attribute__((ext_vector_type(8))) short bf16x8;
typedef __attribute__((ext_vector_type(4))) float f32x4;

union U4 { uint4 v; unsigned int u[4]; bf16x8 h; };

__device__ __forceinline__ unsigned short f2bf(float x) {
    unsigned int u = __float_as_uint(x);
    return (unsigned short)((u + 0x7FFFu + ((u >> 16) & 1u)) >> 16);
}
__device__ __forceinline__ unsigned int pack2(float lo, float hi) {
    return (unsigned int)f2bf(lo) | ((unsigned int)f2bf(hi) << 16);
}
// A fragment: Wt[(k8*M + oc)*4 + j2]
__device__ __forceinline__ bf16x8 loadA(const unsigned int* __restrict__ W, int k8, int M, int oc) {
    U4 r; r.v = *(const uint4*)(W + (((size_t)k8 * M + oc) << 2));
    return r.h;
}
// B fragment (k-panel): one dwordx4 at u32-index (row*BC + b)*4
__device__ __forceinline__ bf16x8 loadB4(const unsigned int* __restrict__ base, size_t idx) {
    U4 r; r.v = *(const uint4*)(base + (idx << 2));
    return r.h;
}
#define MFMA(a, b, c) __builtin_amdgcn_mfma_f32_16x16x32_bf16((a), (b), (c), 0, 0, 0)

// bijective XCD swizzle (m204)
__device__ __forceinline__ int xcd_swz(int L, int nwg) {
    int q = nwg >> 3, r = nwg & 7;
    int x = L & 7, i = L >> 3;
    return (x < r ? x * (q + 1) : r * (q + 1) + (x - r) * q) + i;
}

// k-panel epilogue store: lane writes its 2 u32 (8B) of the out row's uint4
__device__ __forceinline__ void storeK(unsigned int* __restrict__ out,
                                       size_t row, size_t BC, size_t bcol,
                                       int lg, unsigned int u0, unsigned int u1) {
    uint2 v; v.x = u0; v.y = u1;
    *(uint2*)(out + ((row * BC + bcol) << 2) + ((lg & 1) << 1)) = v;
}

// ---------------- weight prepack (bf16, A-fragment layout) ----------------
__global__ __launch_bounds__(256) void prepack(
    const float* __restrict__ W1, const float* __restrict__ W2,
    const float* __restrict__ W3, const float* __restrict__ Wp,
    const float* __restrict__ Wg, const float* __restrict__ Wh1,
    unsigned int* __restrict__ W1t, unsigned int* __restrict__ W2t,
    unsigned int* __restrict__ W3t, unsigned int* __restrict__ Wpt,
    unsigned int* __restrict__ Wgt, unsigned int* __restrict__ Wh1t)
{
    int i = blockIdx.x * 256 + threadIdx.x;
    if (i < 4096) {
        int j2 = i & 3, oc = (i >> 2) & 31, k8 = i >> 7;   // k8 = kh*4+kwp
        int kh = k8 >> 2, kwp = k8 & 3;
        float w[2];
        #pragma unroll
        for (int e = 0; e < 2; e++) {
            int jj = 2 * j2 + e;
            int kwlo = jj >> 2, c = jj & 3;
            w[e] = (c == 3) ? 0.f
                 : W1[((oc * 3 + c) * 8 + kh) * 8 + 2 * kwp + kwlo];
        }
        W1t[i] = pack2(w[0], w[1]);
    } else if (i < 20480) {
        int j = i - 4096;
        int j2 = j & 3, oc = (j >> 2) & 63, k8 = j >> 8;
        int tap = k8 >> 2, ic = (k8 & 3) * 8 + 2 * j2;
        int kh = tap >> 2, kw = tap & 3;
        float a = W2[((oc * 32 + ic) * 4 + kh) * 4 + kw];
        float b = W2[((oc * 32 + ic + 1) * 4 + kh) * 4 + kw];
        W2t[j] = pack2(a, b);
    } else if (i < 38912) {
        int j = i - 20480;
        int j2 = j & 3, oc = (j >> 2) & 63, k8 = j >> 8;
        int tap = k8 >> 3, ic = (k8 & 7) * 8 + 2 * j2;
        int kh = tap / 3, kw = tap % 3;
        float a = W3[((oc * 64 + ic) * 3 + kh) * 3 + kw];
        float b = W3[((oc * 64 + ic + 1) * 3 + kh) * 3 + kw];
        W3t[j] = pack2(a, b);
    } else if (i < 2136064) {
        int j = i - 38912;
        int j2 = j & 3, n = (j >> 2) & 255, k8 = j >> 10;
        int s3 = k8 >> 3, oc = (k8 & 7) * 8 + 2 * j2;
        float a = Wp[(size_t)(oc * 256 + s3) * 256 + n];
        float b = Wp[(size_t)((oc + 1) * 256 + s3) * 256 + n];
        Wpt[j] = pack2(a, b);
    } else if (i < 2168832) {
        int j = i - 2136064;
        int j2 = j & 3, m = (j >> 2) & 255, k8 = j >> 10;
        int k = k8 * 8 + 2 * j2;
        Wgt[j] = pack2(Wg[k * 256 + m], Wg[(k + 1) * 256 + m]);
    } else if (i < 2209792) {
        int j = i - 2168832;
        int j2 = j & 3, m = (j >> 2) & 255, k8 = j >> 10;
        int k = k8 * 8 + 2 * j2;
        Wh1t[j] = pack2(Wh1[k * 256 + m], Wh1[(k + 1) * 256 + m]);
    }
}

// cam [512][84][84][3] fp32 -> camq[(y*42+xp)][b] uint4
__global__ __launch_bounds__(256) void transpose_cam(
    const float* __restrict__ cam, unsigned int* __restrict__ camq, int b0, int BC)
{
    __shared__ float lds[32][253];
    int yy = blockIdx.x;
    int bb = blockIdx.y * 32;
    int t = threadIdx.x;
    for (int f = t; f < 8064; f += 256) {
        int b = f / 252, p = f - b * 252;
        lds[b][p] = cam[(size_t)(b0 + bb + b) * 21168 + yy * 252 + p];
    }
    __syncthreads();
    for (int g = t; g < 1344; g += 256) {
        int b = g & 31, xp = g >> 5;
        const float* l = &lds[b][6 * xp];
        uint4 u;
        u.x = pack2(l[0], l[1]);
        u.y = pack2(l[2], 0.f);
        u.z = pack2(l[3], l[4]);
        u.w = pack2(l[5], 0.f);
        *(uint4*)(camq + (((size_t)(yy * 42 + xp) * BC + bb + b) << 2)) = u;
    }
}

// conv1_pair: 3(+1 pad)ch 84x84 -> 32ch 39x39, k=8 s=2. M=32, K=256.
__global__ __launch_bounds__(256, 3) void conv1_pair(
    const unsigned int* __restrict__ in32, const unsigned int* __restrict__ Wt,
    const float* __restrict__ bias, unsigned int* __restrict__ out32,
    int BC, int nspat)                         // nspat = 780 (20 ohp x 39 ow)
{
    int wgid = xcd_swz(blockIdx.x, gridDim.x);
    int s = wgid % nspat;
    int bq = wgid / nspat;
    int ohp = s / 39, ow = s - ohp * 39;
    int oh0 = 2 * ohp;
    const bool has2 = (oh0 + 1) < 39;
    int wv = threadIdx.x >> 6, l = threadIdx.x & 63;
    int lg = l >> 4, lc = l & 15;
    const size_t sBC = (size_t)BC;
    size_t base = (size_t)bq * 256 + wv * 64 + lc;
    f32x4 acc0[2][4] = {}, acc1[2][4] = {};
    bf16x8 Ar0[2], Ar1[2];
    #pragma unroll
    for (int t = 0; t < 10; t++) {
        const int par = t & 1;
        bf16x8 B[4];
        if (t < 8 || has2) {
            size_t row = (size_t)((2 * oh0 + t) * 42 + ow + lg);
            #pragma unroll
            for (int g = 0; g < 4; g++)
                B[g] = loadB4(in32, row * sBC + base + g * 16);
        }
        if (t >= 2 && has2) {
            #pragma unroll
            for (int g = 0; g < 4; g++) {
                acc1[0][g] = MFMA(Ar0[par], B[g], acc1[0][g]);
                acc1[1][g] = MFMA(Ar1[par], B[g], acc1[1][g]);
            }
        }
        if (t < 8) {
            bf16x8 An0 = loadA(Wt, t * 4 + lg, 32, lc);
            bf16x8 An1 = loadA(Wt, t * 4 + lg, 32, 16 + lc);
            #pragma unroll
            for (int g = 0; g < 4; g++) {
                acc0[0][g] = MFMA(An0, B[g], acc0[0][g]);
                acc0[1][g] = MFMA(An1, B[g], acc0[1][g]);
            }
            Ar0[par] = An0; Ar1[par] = An1;
        }
    }
    int s0 = oh0 * 39 + ow;
    #pragma unroll
    for (int m = 0; m < 2; m++) {
        float4 bv = *(const float4*)(bias + m * 16 + lg * 4);
        size_t row = (size_t)s0 * 4 + 2 * m + (lg >> 1);
        #pragma unroll
        for (int g = 0; g < 4; g++) {
            f32x4 a = acc0[m][g];
            unsigned int u0 = pack2(fmaxf(a.x + bv.x, 0.f), fmaxf(a.y + bv.y, 0.f));
            unsigned int u1 = pack2(fmaxf(a.z + bv.z, 0.f), fmaxf(a.w + bv.w, 0.f));
            storeK(out32, row, sBC, base + g * 16, lg, u0, u1);
        }
        if (has2) {
            size_t row1 = row + 4 * 39;
            #pragma unroll
            for (int g = 0; g < 4; g++) {
                f32x4 a = acc1[m][g];
                unsigned int u0 = pack2(fmaxf(a.x + bv.x, 0.f), fmaxf(a.y + bv.y, 0.f));
                unsigned int u1 = pack2(fmaxf(a.z + bv.z, 0.f), fmaxf(a.w + bv.w, 0.f));
                storeK(out32, row1, sBC, base + g * 16, lg, u0, u1);
            }
        }
    }
}

// conv2: 32ch 39x39 -> 64ch 18x18, k=4 s=2. M=64, K=512. 128-thread blocks.
__global__ __launch_bounds__(128, 3) void conv2_mfma(
    const unsigned int* __restrict__ in32, const unsigned int* __restrict__ Wt,
    const float* __restrict__ bias, unsigned int* __restrict__ out32,
    int BC, int nspat)
{
    int wgid = xcd_swz(blockIdx.x, gridDim.x);
    int s = wgid % nspat;
    int bq = wgid / nspat;                    // 128-b group
    int oh = s / 18, ow = s - oh * 18;
    int wv = threadIdx.x >> 6, l = threadIdx.x & 63;
    int lg = l >> 4, lc = l & 15;
    const size_t sBC = (size_t)BC;
    size_t base = (size_t)bq * 128 + wv * 64 + lc;
    f32x4 acc[4][4] = {};
    int ybase = 2 * oh, xbase = 2 * ow;
    #pragma unroll 1
    for (int sp = 0; sp < 8; sp++) {
        const int s0 = 2 * sp, s1 = s0 + 1;
        bf16x8 A0[4], A1[4], B0[4], B1[4];
        #pragma unroll
        for (int m = 0; m < 4; m++) {
            A0[m] = loadA(Wt, s0 * 4 + lg, 64, m * 16 + lc);
            A1[m] = loadA(Wt, s1 * 4 + lg, 64, m * 16 + lc);
        }
        {
            const int kh = s0 >> 2, kw = s0 & 3;
            size_t row = (size_t)(((ybase + kh) * 39 + xbase + kw) * 4 + lg);
            #pragma unroll
            for (int g = 0; g < 4; g++)
                B0[g] = loadB4(in32, row * sBC + base + g * 16);
        }
        {
            const int kh = s1 >> 2, kw = s1 & 3;
            size_t row = (size_t)(((ybase + kh) * 39 + xbase + kw) * 4 + lg);
            #pragma unroll
            for (int g = 0; g < 4; g++)
                B1[g] = loadB4(in32, row * sBC + base + g * 16);
        }
        #pragma unroll
        for (int m = 0; m < 4; m++)
            #pragma unroll
            for (int g = 0; g < 4; g++)
                acc[m][g] = MFMA(A0[m], B0[g], acc[m][g]);
        #pragma unroll
        for (int m = 0; m < 4; m++)
            #pragma unroll
            for (int g = 0; g < 4; g++)
                acc[m][g] = MFMA(A1[m], B1[g], acc[m][g]);
    }
    #pragma unroll
    for (int m = 0; m < 4; m++) {
        float4 bv = *(const float4*)(bias + m * 16 + lg * 4);
        size_t row = (size_t)s * 8 + 2 * m + (lg >> 1);
        #pragma unroll
        for (int g = 0; g < 4; g++) {
            f32x4 a = acc[m][g];
            unsigned int u0 = pack2(fmaxf(a.x + bv.x, 0.f), fmaxf(a.y + bv.y, 0.f));
            unsigned int u1 = pack2(fmaxf(a.z + bv.z, 0.f), fmaxf(a.w + bv.w, 0.f));
            storeK(out32, row, sBC, base + g * 16, lg, u0, u1);
        }
    }
}

// conv3: 64ch 18x18 -> 64ch 16x16, k=3 s=1. M=64, K=576. 128-thread blocks.
__global__ __launch_bounds__(128, 3) void conv3_mfma(
    const unsigned int* __restrict__ in32, const unsigned int* __restrict__ Wt,
    const float* __restrict__ bias, unsigned int* __restrict__ out32,
    int BC, int nspat)
{
    int wgid = xcd_swz(blockIdx.x, gridDim.x);
    int s = wgid % nspat;
    int bq = wgid / nspat;
    int oh = s >> 4, ow = s & 15;
    int wv = threadIdx.x >> 6, l = threadIdx.x & 63;
    int lg = l >> 4, lc = l & 15;
    const size_t sBC = (size_t)BC;
    size_t base = (size_t)bq * 128 + wv * 64 + lc;
    f32x4 acc[4][4] = {};
    #pragma unroll 1
    for (int sp = 0; sp < 9; sp++) {
        const int s0 = 2 * sp, s1 = s0 + 1;
        const int kh = sp / 3, kw = sp - kh * 3;
        bf16x8 A0[4], A1[4], B0[4], B1[4];
        #pragma unroll
        for (int m = 0; m < 4; m++) {
            A0[m] = loadA(Wt, s0 * 4 + lg, 64, m * 16 + lc);
            A1[m] = loadA(Wt, s1 * 4 + lg, 64, m * 16 + lc);
        }
        size_t row0 = (size_t)(((oh + kh) * 18 + ow + kw) * 8 + lg);
        #pragma unroll
        for (int g = 0; g < 4; g++) {
            B0[g] = loadB4(in32, row0 * sBC + base + g * 16);
            B1[g] = loadB4(in32, (row0 + 4) * sBC + base + g * 16);
        }
        #pragma unroll
        for (int m = 0; m < 4; m++)
            #pragma unroll
            for (int g = 0; g < 4; g++)
                acc[m][g] = MFMA(A0[m], B0[g], acc[m][g]);
        #pragma unroll
        for (int m = 0; m < 4; m++)
            #pragma unroll
            for (int g = 0; g < 4; g++)
                acc[m][g] = MFMA(A1[m], B1[g], acc[m][g]);
    }
    #pragma unroll
    for (int m = 0; m < 4; m++) {
        float4 bv = *(const float4*)(bias + m * 16 + lg * 4);
        size_t row = (size_t)s * 8 + 2 * m + (lg >> 1);
        #pragma unroll
        for (int g = 0; g < 4; g++) {
            f32x4 a = acc[m][g];
            unsigned int u0 = pack2(fmaxf(a.x + bv.x, 0.f), fmaxf(a.y + bv.y, 0.f));
            unsigned int u1 = pack2(fmaxf(a.z + bv.z, 0.f), fmaxf(a.w + bv.w, 0.f));
            storeK(out32, row, sBC, base + g * 16, lg, u0, u1);
        }
    }
}

// proj: x3 k-panel (K=16384) @ Wpt -> partial, K-split 16. 128-thread blocks,
// N=32 per wave (block covers 64 b).
__global__ __launch_bounds__(128, 3) void proj_mfma(
    const unsigned int* __restrict__ x3, const unsigned int* __restrict__ Wpt,
    float* __restrict__ partial, int BC)
{
    int wgid = xcd_swz(blockIdx.x, gridDim.x);
    int rem = wgid & 63;             // 4 mq x 16 kseg
    int b64 = wgid >> 6;
    int mq = rem & 3;
    int kseg = rem >> 2;             // 0..15
    int wv = threadIdx.x >> 6, l = threadIdx.x & 63;
    int lg = l >> 4, lc = l & 15;
    const size_t sBC = (size_t)BC;
    size_t base = (size_t)b64 * 64 + wv * 32 + lc;
    f32x4 acc[4][2] = {};
    #pragma unroll 1
    for (int sp = 0; sp < 16; sp++) {
        const int k8b = kseg * 128 + sp * 8;
        bf16x8 A0[4], A1[4], B0[2], B1[2];
        #pragma unroll
        for (int m = 0; m < 4; m++) {
            A0[m] = loadA(Wpt, k8b + lg, 256, mq * 64 + m * 16 + lc);
            A1[m] = loadA(Wpt, k8b + 4 + lg, 256, mq * 64 + m * 16 + lc);
        }
        #pragma unroll
        for (int g = 0; g < 2; g++) {
            B0[g] = loadB4(x3, (size_t)(k8b + lg) * sBC + base + g * 16);
            B1[g] = loadB4(x3, (size_t)(k8b + 4 + lg) * sBC + base + g * 16);
        }
        #pragma unroll
        for (int m = 0; m < 4; m++)
            #pragma unroll
            for (int g = 0; g < 2; g++)
                acc[m][g] = MFMA(A0[m], B0[g], acc[m][g]);
        #pragma unroll
        for (int m = 0; m < 4; m++)
            #pragma unroll
            for (int g = 0; g < 2; g++)
                acc[m][g] = MFMA(A1[m], B1[g], acc[m][g]);
    }
    #pragma unroll
    for (int m = 0; m < 4; m++) {
        size_t row4 = (size_t)kseg * 64 + mq * 16 + m * 4 + lg;
        #pragma unroll
        for (int g = 0; g < 2; g++)
            *(f32x4*)(partial + ((row4 * sBC + base + g * 16) << 2)) = acc[m][g];
    }
}

// reduce 16 K-split partials + bias + relu -> cf16 k-panel [n8][512] uint4
__global__ __launch_bounds__(256) void reduce_k(
    const float* __restrict__ partial, const float* __restrict__ bp,
    unsigned int* __restrict__ cf16, int b0, int BC, int bcShift)
{
    int i = blockIdx.x * 256 + threadIdx.x;
    int bl = i & (BC - 1);
    int k8 = i >> bcShift;
    f32x4 S0 = {}, S1 = {};
    for (int seg = 0; seg < 16; seg++) {
        const float* p = partial + (((size_t)(seg * 64 + k8 * 2) * BC + bl) << 2);
        S0 += *(const f32x4*)p;
        S1 += *(const f32x4*)(p + (BC << 2));
    }
    int n = k8 * 8;
    uint4 u;
    u.x = pack2(fmaxf(S0.x + bp[n + 0], 0.f), fmaxf(S0.y + bp[n + 1], 0.f));
    u.y = pack2(fmaxf(S0.z + bp[n + 2], 0.f), fmaxf(S0.w + bp[n + 3], 0.f));
    u.z = pack2(fmaxf(S1.x + bp[n + 4], 0.f), fmaxf(S1.y + bp[n + 5], 0.f));
    u.w = pack2(fmaxf(S1.z + bp[n + 6], 0.f), fmaxf(S1.w + bp[n + 7], 0.f));
    *(uint4*)(cf16 + (((size_t)k8 * 512 + b0 + bl) << 2)) = u;
}

// gat_prep: hNb[b][256] = camfeat @ Wg[:256]  (M=256,K=256,N=512)
__global__ __launch_bounds__(64) void gat_prep(
    const unsigned int* __restrict__ cf16, const unsigned int* __restrict__ Wgt,
    float* __restrict__ hNb)
{
    int mq = blockIdx.x, bq = blockIdx.y;
    int l = threadIdx.x, lg = l >> 4, lc = l & 15;
    size_t bcol = (size_t)bq * 32 + lc;
    f32x4 acc[4][2] = {};
    #pragma unroll
    for (int sp = 0; sp < 4; sp++) {
        const int s0 = 2 * sp, s1 = s0 + 1;
        bf16x8 A0[4], A1[4], B0[2], B1[2];
        #pragma unroll
        for (int m = 0; m < 4; m++) {
            A0[m] = loadA(Wgt, s0 * 4 + lg, 256, mq * 64 + m * 16 + lc);
            A1[m] = loadA(Wgt, s1 * 4 + lg, 256, mq * 64 + m * 16 + lc);
        }
        #pragma unroll
        for (int g = 0; g < 2; g++) {
            B0[g] = loadB4(cf16, (size_t)(s0 * 4 + lg) * 512 + bcol + g * 16);
            B1[g] = loadB4(cf16, (size_t)(s1 * 4 + lg) * 512 + bcol + g * 16);
        }
        #pragma unroll
        for (int m = 0; m < 4; m++) {
            acc[m][0] = MFMA(A0[m], B0[0], acc[m][0]);
            acc[m][1] = MFMA(A0[m], B0[1], acc[m][1]);
            acc[m][0] = MFMA(A1[m], B1[0], acc[m][0]);
            acc[m][1] = MFMA(A1[m], B1[1], acc[m][1]);
        }
    }
    #pragma unroll
    for (int m = 0; m < 4; m++) {
        #pragma unroll
        for (int g = 0; g < 2; g++) {
            size_t b = (size_t)bq * 32 + g * 16 + lc;
            int row0 = mq * 64 + m * 16 + lg * 4;
            *(f32x4*)(hNb + b * 256 + row0) = acc[m][g];
        }
    }
}

// gat_mid: per-batch attention row + agent gather + id emb -> af16 k-panel
__global__ __launch_bounds__(256) void gat_mid(
    const float* __restrict__ hNb, const float* __restrict__ pos,
    const float* __restrict__ tpos, const int* __restrict__ aidx,
    const float* __restrict__ Wg, const float* __restrict__ asrc, const float* __restrict__ adst,
    const float* __restrict__ Wid, const float* __restrict__ bid,
    unsigned int* __restrict__ af16)
{
    int b = blockIdx.x, t = threadIdx.x;
    __shared__ float hN[16][256];
    __shared__ float srcv[16][2], dstv[16][2];
    __shared__ float alpha[16][2];
    __shared__ float af[320];
    __shared__ unsigned int adjm_s;

    int ai = aidx[b];
    float basev = hNb[(size_t)b * 256 + t];
    float rw0 = Wg[65536 + t], rw1 = Wg[65792 + t], rw2 = Wg[66048 + t];
    float px = pos[b * 3 + 0], py = pos[b * 3 + 1], pz = pos[b * 3 + 2];
    for (int n = 0; n < 16; n++) {
        float r0 = tpos[(b * 16 + n) * 3 + 0] - px;
        float r1 = tpos[(b * 16 + n) * 3 + 1] - py;
        float r2 = tpos[(b * 16 + n) * 3 + 2] - pz;
        hN[n][t] = basev + r0 * rw0 + r1 * rw1 + r2 * rw2;
    }

    if (t < 64) {
        bool on = false;
        if (t < 16 && t != ai) {
            float dx = tpos[(b * 16 + ai) * 3 + 0] - tpos[(b * 16 + t) * 3 + 0];
            float dy = tpos[(b * 16 + ai) * 3 + 1] - tpos[(b * 16 + t) * 3 + 1];
            float dz = tpos[(b * 16 + ai) * 3 + 2] - tpos[(b * 16 + t) * 3 + 2];
            on = (dx * dx + dy * dy + dz * dz) < 10000.0f;
        }
        unsigned long long m = __ballot(on);
        if (t == 0) adjm_s = (m == 0ull) ? (1u << ai) : (unsigned int)m;
    }
    __syncthreads();

    {
        int p = t >> 3, sub = t & 7;
        int j = p >> 1, h = p & 1;
        float s1 = 0.f, s2 = 0.f;
        #pragma unroll
        for (int dd = 0; dd < 16; dd++) {
            int d = h * 128 + sub * 16 + dd;
            float v = hN[j][d];
            s1 += v * asrc[d];
            s2 += v * adst[d];
        }
        s1 += __shfl_xor(s1, 1); s1 += __shfl_xor(s1, 2); s1 += __shfl_xor(s1, 4);
        s2 += __shfl_xor(s2, 1); s2 += __shfl_xor(s2, 2); s2 += __shfl_xor(s2, 4);
        if (sub == 0) { srcv[j][h] = s1; dstv[j][h] = s2; }
    }
    __syncthreads();

    if (t < 32) {
        int j = t & 15, h = t >> 4;
        unsigned int am = adjm_s;
        float e = srcv[ai][h] + dstv[j][h];
        e = (e > 0.f) ? e : 0.2f * e;
        e = ((am >> j) & 1u) ? e : -1e9f;
        float mx = e;
        mx = fmaxf(mx, __shfl_xor(mx, 1));
        mx = fmaxf(mx, __shfl_xor(mx, 2));
        mx = fmaxf(mx, __shfl_xor(mx, 4));
        mx = fmaxf(mx, __shfl_xor(mx, 8));
        float ex = __expf(e - mx);
        float sm = ex;
        sm += __shfl_xor(sm, 1); sm += __shfl_xor(sm, 2);
        sm += __shfl_xor(sm, 4); sm += __shfl_xor(sm, 8);
        alpha[j][h] = ex / sm;
    }
    __syncthreads();

    {
        int h = t >> 7;
        float o = 0.f;
        #pragma unroll
        for (int j = 0; j < 16; j++) o += alpha[j][h] * hN[j][t];
        o = (o > 0.f) ? o : (__expf(o) - 1.f);
        af[t] = o;
    }
    if (t < 64) {
        float v = (float)ai * Wid[t] + bid[t];
        af[256 + t] = fmaxf(v, 0.f);
    }
    __syncthreads();

    if (t < 40) {
        uint4 u;
        u.x = pack2(af[t * 8 + 0], af[t * 8 + 1]);
        u.y = pack2(af[t * 8 + 2], af[t * 8 + 3]);
        u.z = pack2(af[t * 8 + 4], af[t * 8 + 5]);
        u.w = pack2(af[t * 8 + 6], af[t * 8 + 7]);
        *(uint4*)(af16 + (((size_t)t * 512 + b) << 2)) = u;
    }
}

// head_logits (FUSED): z = relu(af @ Wh1 + bh1) in LDS, then out = z @ Wh2 + bh2.
__global__ __launch_bounds__(256) void head_logits(
    const unsigned int* __restrict__ af16, const unsigned int* __restrict__ Wh1t,
    const float* __restrict__ bh1, const float* __restrict__ Wh2,
    const float* __restrict__ bh2, float* __restrict__ out)
{
    __shared__ float zfs[256][32];   // [row][b-local]
    __shared__ float Ws[1536];
    int bq = blockIdx.x;             // 0..15
    int t = threadIdx.x;
    int mq = t >> 6, l = t & 63, lg = l >> 4, lc = l & 15;
    for (int f = t; f < 1536; f += 256) Ws[f] = Wh2[f];

    size_t bcol = (size_t)bq * 32 + lc;
    f32x4 acc[4][2] = {};
    #pragma unroll
    for (int sp = 0; sp < 5; sp++) {
        const int s0 = 2 * sp, s1 = s0 + 1;
        bf16x8 A0[4], A1[4], B0[2], B1[2];
        #pragma unroll
        for (int m = 0; m < 4; m++) {
            A0[m] = loadA(Wh1t, s0 * 4 + lg, 256, mq * 64 + m * 16 + lc);
            A1[m] = loadA(Wh1t, s1 * 4 + lg, 256, mq * 64 + m * 16 + lc);
        }
        #pragma unroll
        for (int g = 0; g < 2; g++) {
            B0[g] = loadB4(af16, (size_t)(s0 * 4 + lg) * 512 + bcol + g * 16);
            B1[g] = loadB4(af16, (size_t)(s1 * 4 + lg) * 512 + bcol + g * 16);
        }
        #pragma unroll
        for (int m = 0; m < 4; m++) {
            acc[m][0] = MFMA(A0[m], B0[0], acc[m][0]);
            acc[m][1] = MFMA(A0[m], B0[1], acc[m][1]);
            acc[m][0] = MFMA(A1[m], B1[0], acc[m][0]);
            acc[m][1] = MFMA(A1[m], B1[1], acc[m][1]);
        }
    }
    #pragma unroll
    for (int m = 0; m < 4; m++) {
        int row0 = mq * 64 + m * 16 + lg * 4;
        float4 bv = *(const float4*)(bh1 + row0);
        #pragma unroll
        for (int g = 0; g < 2; g++) {
            f32x4 a = acc[m][g];
            int bl = g * 16 + lc;
            zfs[row0 + 0][bl] = fmaxf(a.x + bv.x, 0.f);
            zfs[row0 + 1][bl] = fmaxf(a.y + bv.y, 0.f);
            zfs[row0 + 2][bl] = fmaxf(a.z + bv.z, 0.f);
            zfs[row0 + 3][bl] = fmaxf(a.w + bv.w, 0.f);
        }
    }
    __syncthreads();

    if (t < 192) {
        int b = t & 31, j = t >> 5;          // j = 0..5
        float s = bh2[j];
        #pragma unroll 8
        for (int k = 0; k < 256; k++) s += zfs[k][b] * Ws[k * 6 + j];
        out[(bq * 32 + b) * 6 + j] = s;
    }
}

extern "C" void kernel_launch(void* const* d_in, const int* in_sizes, int n_in,
                              void* d_out, int out_size, void* d_ws, size_t ws_size,
                              hipStream_t stream)
{
    const float* cam  = (const float*)d_in[0];
    const float* pos  = (const float*)d_in[1];
    const float* tpos = (const float*)d_in[2];
    const int*   aidx = (const int*)d_in[3];
    const float* W1   = (const float*)d_in[4];
    const float* b1   = (const float*)d_in[5];
    const float* W2   = (const float*)d_in[6];
    const float* b2   = (const float*)d_in[7];
    const float* W3   = (const float*)d_in[8];
    const float* b3   = (const float*)d_in[9];
    const float* Wp   = (const float*)d_in[10];
    const float* bp   = (const float*)d_in[11];
    const float* Wid  = (const float*)d_in[12];
    const float* bid  = (const float*)d_in[13];
    const float* Wg   = (const float*)d_in[14];
    const float* asrc = (const float*)d_in[15];
    const float* adst = (const float*)d_in[16];
    const float* Wh1  = (const float*)d_in[17];
    const float* bh1  = (const float*)d_in[18];
    const float* Wh2  = (const float*)d_in[19];
    const float* bh2  = (const float*)d_in[20];
    float* out = (float*)d_out;

    // per-chunk u32 = 50736*BC ; fixed u32 = 2,488,320
    int BC = 256;
    if (((size_t)50736 * 512 + 2488320) * 4 <= ws_size) BC = 512;
    int bcShift = (BC == 512) ? 9 : 8;
    int nbq2 = BC >> 8;                        // 256-b groups
    int nbq7 = BC >> 7;                        // 128-b groups
    int nbq6 = BC >> 6;                        // 64-b groups

    unsigned int* ws32 = (unsigned int*)d_ws;
    unsigned int* RA  = ws32;                                  // camq (14112*BC) / out2 (10368*BC)
    unsigned int* RB  = RA + (size_t)14112 * BC;               // out1 (24336*BC)
    unsigned int* RC  = RB + (size_t)24336 * BC;               // x3   (8192*BC)
    float*        RD  = (float*)(RC + (size_t)8192 * BC);      // partial (4096*BC f32)
    unsigned int* W1t = (unsigned int*)(RD + (size_t)4096 * BC);
    unsigned int* W2t  = W1t + 4096;
    unsigned int* W3t  = W2t + 16384;
    unsigned int* Wpt  = W3t + 18432;
    unsigned int* Wgt  = Wpt + 2097152;
    unsigned int* Wh1t = Wgt + 32768;
    unsigned int* cf16 = Wh1t + 40960;                         // 32 x 512 uint4
    float*        hNb  = (float*)(cf16 + 65536);               // 512 x 256 f32
    unsigned int* af16 = (unsigned int*)(hNb + 131072);        // 40 x 512 uint4

    prepack<<<8632, 256, 0, stream>>>(W1, W2, W3, Wp, Wg, Wh1,
                                      W1t, W2t, W3t, Wpt, Wgt, Wh1t);

    for (int b0 = 0; b0 < 512; b0 += BC) {
        transpose_cam<<<dim3(84, BC / 32), 256, 0, stream>>>(cam, RA, b0, BC);
        conv1_pair<<<780 * nbq2, 256, 0, stream>>>(RA, W1t, b1, RB, BC, 780);
        conv2_mfma<<<324 * nbq7, 128, 0, stream>>>(RB, W2t, b2, RA, BC, 324);
        conv3_mfma<<<256 * nbq7, 128, 0, stream>>>(RA, W3t, b3, RC, BC, 256);
        proj_mfma<<<64 * nbq6, 128, 0, stream>>>(RC, Wpt, RD, BC);
        reduce_k<<<(32 * BC) / 256, 256, 0, stream>>>(RD, bp, cf16, b0, BC, bcShift);
    }
    gat_prep<<<dim3(4, 16), 64, 0, stream>>>(cf16, Wgt, hNb);
    gat_mid<<<512, 256, 0, stream>>>(hNb, pos, tpos, aidx, Wg, asrc, adst,
                                     Wid, bid, af16);
    head_logits<<<16, 256, 0, stream>>>(af16, Wh1t, bh1, Wh2, bh2, out);
}